// Round 9
// baseline (2994.080 us; speedup 1.0000x reference)
//
#include <hip/hip_runtime.h>
#include <stdint.h>

typedef short bf8 __attribute__((ext_vector_type(8)));   // 8 bf16 (4 VGPRs)
typedef float f4  __attribute__((ext_vector_type(4)));   // MFMA acc
typedef unsigned short u16;
typedef unsigned int   u32;
typedef unsigned long long u64;

#define LOG2E 1.4426950408889634f

__device__ __forceinline__ u16 f2bf(float f){
  uint32_t u = __builtin_bit_cast(uint32_t, f);
  u += 0x7fffu + ((u >> 16) & 1u);
  return (u16)(u >> 16);
}
// sigmoid of value pre-scaled by log2e: 1/(1+2^-a)
__device__ __forceinline__ float sigm_ps(float a){
  return __builtin_amdgcn_rcpf(1.0f + __builtin_amdgcn_exp2f(-a));
}
// LDS-only barrier: don't drain vmcnt
__device__ __forceinline__ void bar_lds(){
  asm volatile("s_waitcnt lgkmcnt(0)\n\ts_barrier" ::: "memory");
}
// volatile 16B load: stays in the loop (no LICM -> no spill pathology)
__device__ __forceinline__ bf8 vload16(const u16* p){
  return *(const volatile bf8*)p;
}

// ---------------------------------------------------------------------------
// Prep: prescaled bf16 weights W0c[512][160]=[Whh0|Wih0|0], W1c[512][256]=
// [Whh1|Wih1]; rows scaled log2e (i,f,o) / 2*log2e (g); prescaled biases.
// ---------------------------------------------------------------------------
__global__ void prep_kernel(const float* __restrict__ Wih0, const float* __restrict__ Whh0,
                            const float* __restrict__ bih0, const float* __restrict__ bhh0,
                            const float* __restrict__ Wih1, const float* __restrict__ Whh1,
                            const float* __restrict__ bih1, const float* __restrict__ bhh1,
                            u16* __restrict__ W0c, u16* __restrict__ W1c,
                            float* __restrict__ bias0, float* __restrict__ bias1){
  int g = blockIdx.x;      // gate row 0..511
  int t = threadIdx.x;     // 0..63
  float s = (g >= 256 && g < 384) ? 2.0f * LOG2E : LOG2E;
  for(int k = t; k < 160; k += 64){
    float v = 0.0f;
    if(k < 128)      v = Whh0[g*128 + k];
    else if(k < 146) v = Wih0[g*18 + (k-128)];
    W0c[g*160 + k] = f2bf(v * s);
  }
  for(int k = t; k < 256; k += 64){
    float v = (k < 128) ? Whh1[g*128 + k] : Wih1[g*128 + (k-128)];
    W1c[g*256 + k] = f2bf(v * s);
  }
  if(t == 0){
    bias0[g] = (bih0[g] + bhh0[g]) * s;
    bias1[g] = (bih1[g] + bhh1[g]) * s;
  }
}

// ===========================================================================
// BOTH layers in one block, pipelined in time: iteration i runs L1 step i-1
// then L0 step i; h1 crosses layers through LDS only. 64 blocks x 256 thr
// (4 waves = 1 wave/SIMD -> 512-reg budget), 8 batch rows/block.
// Wave w owns comps [32w,32w+32) (j=0,1 16-tiles) for all 4 gate types.
// MFMA: A=weights (M=gates), B=state (N=16; cols 8-15 dup rows 0-7).
// acc[q][r]: col=row(l15), m=quad*4+r = comp-within-16. Lane keeps comps
// {jc, jc+1} (jc=32w+16j+4quad+(up?2:0)) -> pure per-lane cndmask select.
// LDS bufs [kc][8 rows][8] (conflict-free): slot k at [k>>3][row][k&7].
// A1's h1-part weights (32 frags) are re-loaded per step via volatile b128
// (L2-hot) to keep peak registers ~460.
// One bar_lds per iteration; buffers parity-switched by i&1.
// ===========================================================================
__global__ __launch_bounds__(256, 1)
void lstm_both(const u16* __restrict__ Wc0, const u16* __restrict__ Wc1,
               const float* __restrict__ bias0, const float* __restrict__ bias1,
               const float* __restrict__ xin,   // (512,512,18) f32
               const float* __restrict__ Wfc1, const float* __restrict__ bfc1,
               const float* __restrict__ Wfc2, const float* __restrict__ bfc2,
               float* __restrict__ out)         // (512,) f32
{
  __shared__ __align__(16) u16  h0S[2][20][8][8];  // L0 state: h(16kc)+x(4kc)
  __shared__ __align__(16) u16  h1T[2][16][8][8];  // L0 -> L1 transfer
  __shared__ __align__(16) u16  h2S[2][16][8][8];  // L1 state
  __shared__ __align__(16) float ffin[8][132];     // final h2 f32

  const int tid  = threadIdx.x;
  const int wave = tid >> 6;
  const int lane = tid & 63;
  const int quad = lane >> 4;
  const int l15  = lane & 15;
  const bool up  = (l15 >= 8);
  const int row  = l15 & 7;
  const int rowbase = blockIdx.x * 8;
  const int kcq  = quad >> 1;
  const int eo   = 4*(quad & 1) + (up ? 2 : 0);

  // ---- static A-frags: L0 all of K=160; L1 h2-part (K cols 0..127)
  bf8 A0[4][2][5];
  bf8 A1[4][2][4];
#pragma unroll
  for(int q = 0; q < 4; q++){
#pragma unroll
    for(int j = 0; j < 2; j++){
      const int gr = 128*q + 32*wave + 16*j + l15;
      const u16* w0 = Wc0 + (u64)gr*160 + quad*8;
      const u16* w1 = Wc1 + (u64)gr*256 + quad*8;
#pragma unroll
      for(int kt = 0; kt < 5; kt++) A0[q][j][kt] = *(const bf8*)(w0 + kt*32);
#pragma unroll
      for(int kt = 0; kt < 4; kt++) A1[q][j][kt] = *(const bf8*)(w1 + kt*32);
    }
  }
  // per-lane biases for the lane's own comp pair {jc, jc+1}
  float2 b0[4][2], b1[4][2];
#pragma unroll
  for(int q = 0; q < 4; q++){
#pragma unroll
    for(int j = 0; j < 2; j++){
      const int jc = 32*wave + 16*j + 4*quad + (up ? 2 : 0);
      b0[q][j] = *(const float2*)(bias0 + 128*q + jc);
      b1[q][j] = *(const float2*)(bias1 + 128*q + jc);
    }
  }

  float cL0[4] = {0.f,0.f,0.f,0.f};   // [2*j + pair-slot]
  float cL1[4] = {0.f,0.f,0.f,0.f};
  float hv[4]  = {0.f,0.f,0.f,0.f};   // final h2 of this lane's comps

  // zero all state buffers (h=0 init; x pad slots stay 0)
  for(int i = tid; i < 2*20*8*8; i += 256) ((u16*)h0S)[i] = 0;
  for(int i = tid; i < 2*16*8*8; i += 256) ((u16*)h1T)[i] = 0;
  for(int i = tid; i < 2*16*8*8; i += 256) ((u16*)h2S)[i] = 0;
  __syncthreads();
  int sr = 0, sk = 0;
  if(tid < 144){
    sr = tid/18; sk = tid - 18*sr;
    h0S[0][16+(sk>>3)][sr][sk&7] = f2bf(xin[((u64)(rowbase+sr)*512)*18 + sk]);
  }
  __syncthreads();

  for(int i = 0; i <= 512; i++){
    const int pi = i & 1;
    // prefetch x(i+1)
    float xv = 0.f;
    if(tid < 144 && i < 511)
      xv = xin[((u64)(rowbase+sr)*512 + (i+1))*18 + sk];

    // ---------------- L1 phase: step t = i-1 ----------------
    if(i >= 1){
      const int c1 = pi ^ 1;
      bf8 Bh2[4], Bh1[4];
#pragma unroll
      for(int kt = 0; kt < 4; kt++) Bh2[kt] = *(const bf8*)&h2S[c1][kt*4+quad][row][0];
#pragma unroll
      for(int kh = 0; kh < 4; kh++) Bh1[kh] = *(const bf8*)&h1T[c1][kh*4+quad][row][0];
#pragma unroll
      for(int j = 0; j < 2; j++){
        // per-step volatile reload of W1's h1-part frags (L2-hot)
        bf8 Wh1[4][4];
#pragma unroll
        for(int q = 0; q < 4; q++){
          const u16* wp = Wc1 + (u64)(128*q + 32*wave + 16*j + l15)*256 + 128 + quad*8;
#pragma unroll
          for(int kh = 0; kh < 4; kh++) Wh1[q][kh] = vload16(wp + kh*32);
        }
        f4 acc[4];
#pragma unroll
        for(int q = 0; q < 4; q++){ f4 z = {0.f,0.f,0.f,0.f}; acc[q] = z; }
#pragma unroll
        for(int kt = 0; kt < 4; kt++){
#pragma unroll
          for(int q = 0; q < 4; q++)
            acc[q] = __builtin_amdgcn_mfma_f32_16x16x32_bf16(A1[q][j][kt], Bh2[kt], acc[q], 0,0,0);
        }
#pragma unroll
        for(int kh = 0; kh < 4; kh++){
#pragma unroll
          for(int q = 0; q < 4; q++)
            acc[q] = __builtin_amdgcn_mfma_f32_16x16x32_bf16(Wh1[q][kh], Bh1[kh], acc[q], 0,0,0);
        }
        // act (2 comps; upper lanes select dup regs 2,3)
        float ga[4], gb[4];
#pragma unroll
        for(int q = 0; q < 4; q++){
          ga[q] = (up ? acc[q][2] : acc[q][0]) + b1[q][j].x;
          gb[q] = (up ? acc[q][3] : acc[q][1]) + b1[q][j].y;
        }
        float ia = sigm_ps(ga[0]), fa = sigm_ps(ga[1]);
        float Ga = 2.f*sigm_ps(ga[2]) - 1.f, oa = sigm_ps(ga[3]);
        cL1[2*j] = fa*cL1[2*j] + ia*Ga;
        float ha = oa * (2.f*sigm_ps(cL1[2*j]*(2.f*LOG2E)) - 1.f);
        float ib = sigm_ps(gb[0]), fb = sigm_ps(gb[1]);
        float Gb = 2.f*sigm_ps(gb[2]) - 1.f, ob = sigm_ps(gb[3]);
        cL1[2*j+1] = fb*cL1[2*j+1] + ib*Gb;
        float hb = ob * (2.f*sigm_ps(cL1[2*j+1]*(2.f*LOG2E)) - 1.f);
        u32 pair = (u32)f2bf(ha) | ((u32)f2bf(hb) << 16);
        *(u32*)&h2S[pi][4*wave + 2*j + kcq][row][eo] = pair;
        if(i == 512){ hv[2*j] = ha; hv[2*j+1] = hb; }
      }
    }

    // ---------------- L0 phase: step t = i ----------------
    if(i < 512){
      bf8 B0[5];
#pragma unroll
      for(int kt = 0; kt < 5; kt++) B0[kt] = *(const bf8*)&h0S[pi][kt*4+quad][row][0];
#pragma unroll
      for(int j = 0; j < 2; j++){
        f4 acc[4];
#pragma unroll
        for(int q = 0; q < 4; q++){ f4 z = {0.f,0.f,0.f,0.f}; acc[q] = z; }
#pragma unroll
        for(int kt = 0; kt < 5; kt++){
#pragma unroll
          for(int q = 0; q < 4; q++)
            acc[q] = __builtin_amdgcn_mfma_f32_16x16x32_bf16(A0[q][j][kt], B0[kt], acc[q], 0,0,0);
        }
        float ga[4], gb[4];
#pragma unroll
        for(int q = 0; q < 4; q++){
          ga[q] = (up ? acc[q][2] : acc[q][0]) + b0[q][j].x;
          gb[q] = (up ? acc[q][3] : acc[q][1]) + b0[q][j].y;
        }
        float ia = sigm_ps(ga[0]), fa = sigm_ps(ga[1]);
        float Ga = 2.f*sigm_ps(ga[2]) - 1.f, oa = sigm_ps(ga[3]);
        cL0[2*j] = fa*cL0[2*j] + ia*Ga;
        float ha = oa * (2.f*sigm_ps(cL0[2*j]*(2.f*LOG2E)) - 1.f);
        float ib = sigm_ps(gb[0]), fb = sigm_ps(gb[1]);
        float Gb = 2.f*sigm_ps(gb[2]) - 1.f, ob = sigm_ps(gb[3]);
        cL0[2*j+1] = fb*cL0[2*j+1] + ib*Gb;
        float hb = ob * (2.f*sigm_ps(cL0[2*j+1]*(2.f*LOG2E)) - 1.f);
        u32 pair = (u32)f2bf(ha) | ((u32)f2bf(hb) << 16);
        const int kc = 4*wave + 2*j + kcq;
        *(u32*)&h0S[pi^1][kc][row][eo] = pair;   // recurrent state
        *(u32*)&h1T[pi][kc][row][eo]  = pair;    // hand-off to L1
      }
      if(tid < 144 && i < 511)
        h0S[pi^1][16+(sk>>3)][sr][sk&7] = f2bf(xv);
    }
    bar_lds();
  }

  // ---- FC head
#pragma unroll
  for(int j = 0; j < 2; j++){
    const int jc = 32*wave + 16*j + 4*quad + (up ? 2 : 0);
    ffin[row][jc]   = hv[2*j];
    ffin[row][jc+1] = hv[2*j+1];
  }
  __syncthreads();
#pragma unroll
  for(int rr = 0; rr < 2; rr++){
    int r = 2*wave + rr;
    float s = bfc1[lane];
    const float* wrow = Wfc1 + lane*128;
    for(int j = 0; j < 128; j++) s = fmaf(wrow[j], ffin[r][j], s);
    float term = fmaxf(s, 0.f) * Wfc2[lane];
#pragma unroll
    for(int off = 32; off > 0; off >>= 1) term += __shfl_down(term, off);
    if(lane == 0) out[rowbase + r] = sigm_ps((term + bfc2[0]) * LOG2E);
  }
}

// ---------------------------------------------------------------------------
extern "C" void kernel_launch(void* const* d_in, const int* in_sizes, int n_in,
                              void* d_out, int out_size, void* d_ws, size_t ws_size,
                              hipStream_t stream){
  const float* x    = (const float*)d_in[0];
  const float* Wih0 = (const float*)d_in[1];
  const float* Whh0 = (const float*)d_in[2];
  const float* bih0 = (const float*)d_in[3];
  const float* bhh0 = (const float*)d_in[4];
  const float* Wih1 = (const float*)d_in[5];
  const float* Whh1 = (const float*)d_in[6];
  const float* bih1 = (const float*)d_in[7];
  const float* bhh1 = (const float*)d_in[8];
  const float* Wfc1 = (const float*)d_in[9];
  const float* bfc1 = (const float*)d_in[10];
  const float* Wfc2 = (const float*)d_in[11];
  const float* bfc2 = (const float*)d_in[12];

  char* ws = (char*)d_ws;
  u16*   W0c   = (u16*)(ws);                       // 512*160*2 = 163840 B
  u16*   W1c   = (u16*)(ws + 163840);              // 512*256*2 = 262144 B
  float* bias0 = (float*)(ws + 163840 + 262144);   // 2048 B
  float* bias1 = bias0 + 512;                      // 2048 B

  prep_kernel<<<dim3(512), dim3(64), 0, stream>>>(Wih0, Whh0, bih0, bhh0,
                                                  Wih1, Whh1, bih1, bhh1,
                                                  W0c, W1c, bias0, bias1);

  lstm_both<<<dim3(64), dim3(256), 0, stream>>>(
      W0c, W1c, bias0, bias1, x,
      Wfc1, bfc1, Wfc2, bfc2, (float*)d_out);
}